// Round 1
// baseline (1549.425 us; speedup 1.0000x reference)
//
#include <hip/hip_runtime.h>
#include <cmath>

// Multi-scale residual VQ (VAR VectorQuantizer2 hot path), fp32 baseline.
// B=64, C=32, H=W=16, V=4096, 10 scales pn=1..16, SHARE_K=4, RESI=0.5.
// pn=16 scale uses the same down/up kernels: area & bicubic matrices are
// exactly identity there (cubic(0)=1, cubic(1)=0 exact in fp).

#define BB 64
#define CC 32
#define HHW 16
#define VV 4096
#define GRP 16           // argmin code groups (parallelism at small scales)
#define GSZ (VV / GRP)   // 256 codes per group

__device__ __forceinline__ double cubicw(double x) {
    x = fabs(x);
    const double a = -0.75;
    if (x <= 1.0) return ((a + 2.0) * x - (a + 3.0)) * x * x + 1.0;
    if (x < 2.0)  return (((a * x - 5.0 * a) * x + 8.0 * a) * x - 4.0 * a);
    return 0.0;
}

__global__ void init_k(const float* __restrict__ f, const float* __restrict__ E,
                       float* __restrict__ f_rest, float* __restrict__ f_hat,
                       float* __restrict__ e2) {
    int i = blockIdx.x * 256 + threadIdx.x;
    if (i < BB * CC * HHW * HHW) { f_rest[i] = f[i]; f_hat[i] = 0.f; }
    if (i < VV) {
        float s = 0.f;
        #pragma unroll
        for (int c = 0; c < CC; ++c) { float e = E[i * CC + c]; s += e * e; }
        e2[i] = s;
    }
}

// z[((b*pn+p)*pn+q)*C + c] = area-downsample of f_rest  (identity at pn=16)
__global__ void down_k(const float* __restrict__ f_rest, float* __restrict__ z, int pn) {
    int id = blockIdx.x * 256 + threadIdx.x;
    int total = BB * pn * pn * CC;
    if (id >= total) return;
    int c = id & (CC - 1);
    int r = id >> 5;
    int q = r % pn; r /= pn;
    int p = r % pn; int b = r / pn;
    int sp = (p * HHW) / pn, ep = ((p + 1) * HHW + pn - 1) / pn;
    int sq = (q * HHW) / pn, eq = ((q + 1) * HHW + pn - 1) / pn;
    float wgt = 1.0f / ((float)(ep - sp) * (float)(eq - sq));
    const float* src = f_rest + ((size_t)(b * CC + c)) * HHW * HHW;
    float s = 0.f;
    for (int h = sp; h < ep; ++h)
        for (int w = sq; w < eq; ++w)
            s += src[h * HHW + w];
    z[id] = s * wgt;
}

// One thread per point; each block-column (blockIdx.y) scans a 256-code group.
// E-row loads are wave-uniform (v uniform across lanes) -> scalar cache path.
__global__ void argmin_k(const float* __restrict__ z, const float* __restrict__ E,
                         const float* __restrict__ e2,
                         float* __restrict__ bestd, int* __restrict__ bestv, int M) {
    int m = blockIdx.x * 64 + threadIdx.x;
    int g = blockIdx.y;
    if (m >= M) return;
    float zr[CC];
    float z2 = 0.f;
    #pragma unroll
    for (int c = 0; c < CC; ++c) { zr[c] = z[(size_t)m * CC + c]; z2 += zr[c] * zr[c]; }
    int v0 = g * GSZ;
    float best = 3.4e38f; int bv = v0;
    for (int v = v0; v < v0 + GSZ; ++v) {
        const float* e = E + (size_t)v * CC;
        float dot = 0.f;
        #pragma unroll
        for (int c = 0; c < CC; ++c) dot += zr[c] * e[c];
        float d = z2 - 2.0f * dot + e2[v];
        if (d < best) { best = d; bv = v; }   // strict < keeps smallest v (numpy argmin)
    }
    bestd[(size_t)m * GRP + g] = best;
    bestv[(size_t)m * GRP + g] = bv;
}

__global__ void argmin_reduce_k(const float* __restrict__ bestd, const int* __restrict__ bestv,
                                int* __restrict__ idx, int M) {
    int m = blockIdx.x * 256 + threadIdx.x;
    if (m >= M) return;
    float best = bestd[(size_t)m * GRP]; int bv = bestv[(size_t)m * GRP];
    for (int g = 1; g < GRP; ++g) {
        float d = bestd[(size_t)m * GRP + g];
        if (d < best) { best = d; bv = bestv[(size_t)m * GRP + g]; }  // later groups have larger v
    }
    idx[m] = bv;
}

// Vertical bicubic upsample fused with codebook gather:
// tmp[((b*C+c)*16+h)*pn+q] = sum_k w_k * E[idx[(b*pn+j)*pn+q], c]
__global__ void upv_k(const int* __restrict__ idx, const float* __restrict__ E,
                      float* __restrict__ tmp, int pn) {
    int id = blockIdx.x * 256 + threadIdx.x;
    int total = BB * CC * HHW * pn;
    if (id >= total) return;
    int q = id % pn; int r = id / pn;
    int h = r % HHW; r /= HHW;
    int c = r % CC;  int b = r / CC;
    double src = (h + 0.5) * (double)pn / (double)HHW - 0.5;
    double fi = floor(src);
    int i0 = (int)fi;
    double t = src - fi;
    float s = 0.f;
    #pragma unroll
    for (int k = -1; k <= 2; ++k) {
        int j = i0 + k; j = j < 0 ? 0 : (j > pn - 1 ? pn - 1 : j);
        float wgt = (float)cubicw((double)k - t);
        int mm = (b * pn + j) * pn + q;
        s += wgt * E[(size_t)idx[mm] * CC + c];
    }
    tmp[id] = s;
}

// Horizontal bicubic: hup[b,c,h,w] = sum_k w_k * tmp[b,c,h,j]
__global__ void uph_k(const float* __restrict__ tmp, float* __restrict__ hup, int pn) {
    int id = blockIdx.x * 256 + threadIdx.x;
    if (id >= BB * CC * HHW * HHW) return;
    int w = id % HHW; int r = id / HHW;
    int h = r % HHW; r /= HHW;
    int c = r % CC;  int b = r / CC;
    double src = (w + 0.5) * (double)pn / (double)HHW - 0.5;
    double fi = floor(src); int i0 = (int)fi; double t = src - fi;
    const float* row = tmp + ((size_t)(b * CC + c) * HHW + h) * pn;
    float s = 0.f;
    #pragma unroll
    for (int k = -1; k <= 2; ++k) {
        int j = i0 + k; j = j < 0 ? 0 : (j > pn - 1 ? pn - 1 : j);
        float wgt = (float)cubicw((double)k - t);
        s += wgt * row[j];
    }
    hup[id] = s;
}

// Phi(h) = 0.5*h + 0.5*(conv3x3(h)+b); then f_hat += Phi, f_rest -= Phi.
// Weights are wave-uniform (co fixed per 256-thread tile) -> scalar cache.
__global__ void phi_k(const float* __restrict__ hup, const float* __restrict__ pw,
                      const float* __restrict__ pb, float* __restrict__ f_hat,
                      float* __restrict__ f_rest, int k) {
    int id = blockIdx.x * 256 + threadIdx.x;
    if (id >= BB * CC * HHW * HHW) return;
    int w = id % HHW; int r = id / HHW;
    int h = r % HHW; r /= HHW;
    int co = r % CC; int b = r / CC;
    const float* wk = pw + ((size_t)k * CC + co) * CC * 9;
    float acc = pb[k * CC + co];
    for (int ci = 0; ci < CC; ++ci) {
        const float* x = hup + (size_t)(b * CC + ci) * HHW * HHW;
        const float* ww = wk + ci * 9;
        #pragma unroll
        for (int kh = 0; kh < 3; ++kh) {
            int hh = h + kh - 1;
            if (hh < 0 || hh >= HHW) continue;
            #pragma unroll
            for (int kw = 0; kw < 3; ++kw) {
                int wi = w + kw - 1;
                if (wi < 0 || wi >= HHW) continue;
                acc += x[hh * HHW + wi] * ww[kh * 3 + kw];
            }
        }
    }
    float hc = hup[id];
    float hf = 0.5f * hc + 0.5f * acc;
    f_hat[id] += hf;
    f_rest[id] -= hf;
}

extern "C" void kernel_launch(void* const* d_in, const int* in_sizes, int n_in,
                              void* d_out, int out_size, void* d_ws, size_t ws_size,
                              hipStream_t stream) {
    const float* f  = (const float*)d_in[0];
    const float* E  = (const float*)d_in[1];
    const float* pw = (const float*)d_in[2];
    const float* pb = (const float*)d_in[3];
    float* out = (float*)d_out;

    const int N = BB * CC * HHW * HHW;  // 524288
    float* wsf    = (float*)d_ws;
    float* f_rest = wsf;
    float* z      = wsf + (size_t)N;
    float* tmp    = wsf + (size_t)2 * N;
    float* hup    = wsf + (size_t)3 * N;
    float* e2     = wsf + (size_t)4 * N;
    float* bestd  = e2 + VV;
    int*   bestv  = (int*)(bestd + 16384 * GRP);
    int*   idx    = bestv + 16384 * GRP;

    // Replicate numpy _phi_select bit-exactly in IEEE double (ties at si=2,7).
    int phik[10];
    {
        double start = 1.0 / 3.0 / 4.0;
        double stop  = 1.0 - 1.0 / 3.0 / 4.0;
        double step  = (stop - start) / 3.0;
        double ticks[4];
        for (int i = 0; i < 4; ++i) ticks[i] = (double)i * step + start;
        ticks[3] = stop;
        for (int si = 0; si < 10; ++si) {
            double s = (double)si / 9.0;
            int bk = 0; double bd = fabs(ticks[0] - s);
            for (int t = 1; t < 4; ++t) {
                double d2 = fabs(ticks[t] - s);
                if (d2 < bd) { bd = d2; bk = t; }
            }
            phik[si] = bk;
        }
    }

    static const int pns[10] = {1, 2, 3, 4, 5, 6, 8, 10, 13, 16};

    init_k<<<(N + 255) / 256, 256, 0, stream>>>(f, E, f_rest, out, e2);

    for (int si = 0; si < 10; ++si) {
        int pn = pns[si];
        int M = BB * pn * pn;
        int n1 = M * CC;
        down_k<<<(n1 + 255) / 256, 256, 0, stream>>>(f_rest, z, pn);
        dim3 ag((M + 63) / 64, GRP);
        argmin_k<<<ag, 64, 0, stream>>>(z, E, e2, bestd, bestv, M);
        argmin_reduce_k<<<(M + 255) / 256, 256, 0, stream>>>(bestd, bestv, idx, M);
        int n2 = BB * CC * HHW * pn;
        upv_k<<<(n2 + 255) / 256, 256, 0, stream>>>(idx, E, tmp, pn);
        uph_k<<<(N + 255) / 256, 256, 0, stream>>>(tmp, hup, pn);
        phi_k<<<(N + 255) / 256, 256, 0, stream>>>(hup, pw, pb, out, f_rest, phik[si]);
    }
}

// Round 2
// 829.877 us; speedup vs baseline: 1.8671x; 1.8671x over previous
//
#include <hip/hip_runtime.h>
#include <cmath>

// Multi-scale residual VQ, round 2: fused per-scale pipeline.
// B=64, C=32, H=W=16, V=4096, scales pn=1..16.
// Per scale: down_k (area, si<9) -> argmin_k (grouped) -> fuse_k
// (group-reduce + gather + separable bicubic in LDS + 3x3 conv Phi + update).

#define BB 64
#define CC 32
#define HH 16
#define VV 4096
#define NTOT (BB*CC*HH*HH)   // 524288

__device__ __forceinline__ double cubicw(double x) {
    x = fabs(x);
    const double a = -0.75;
    if (x <= 1.0) return ((a + 2.0) * x - (a + 3.0)) * x * x + 1.0;
    if (x < 2.0)  return (((a * x - 5.0 * a) * x + 8.0 * a) * x - 4.0 * a);
    return 0.0;
}

__global__ void init_k(const float* __restrict__ f, const float* __restrict__ E,
                       float* __restrict__ f_rest, float* __restrict__ f_hat,
                       float* __restrict__ e2) {
    int i = blockIdx.x * 256 + threadIdx.x;
    if (i < NTOT) { f_rest[i] = f[i]; f_hat[i] = 0.f; }
    if (i < VV) {
        float s = 0.f;
        #pragma unroll
        for (int c = 0; c < CC; ++c) { float e = E[i * CC + c]; s += e * e; }
        e2[i] = s;
    }
}

// z[((b*pn+p)*pn+q)*C + c] = area-downsample of f_rest (si<9 only)
__global__ void down_k(const float* __restrict__ f_rest, float* __restrict__ z, int pn) {
    int id = blockIdx.x * 256 + threadIdx.x;
    int total = BB * pn * pn * CC;
    if (id >= total) return;
    int c = id & (CC - 1);
    int r = id >> 5;
    int q = r % pn; r /= pn;
    int p = r % pn; int b = r / pn;
    int sp = (p * HH) / pn, ep = ((p + 1) * HH + pn - 1) / pn;
    int sq = (q * HH) / pn, eq = ((q + 1) * HH + pn - 1) / pn;
    float wgt = 1.0f / ((float)(ep - sp) * (float)(eq - sq));
    const float* src = f_rest + ((size_t)(b * CC + c)) * HH * HH;
    float s = 0.f;
    for (int h = sp; h < ep; ++h)
        for (int w = sq; w < eq; ++w)
            s += src[h * HH + w];
    z[id] = s * wgt;
}

// Grouped argmin: block 256 threads (one point each), blockIdx.y = code group.
// DIRECT=1 reads f_rest (channel-major) for the identity pn=16 scale.
template<int DIRECT>
__global__ __launch_bounds__(256) void argmin_k(const float* __restrict__ zin,
                         const float* __restrict__ E, const float* __restrict__ e2,
                         float* __restrict__ bestd, int* __restrict__ bestv,
                         int M, int gsz) {
    int m = blockIdx.x * 256 + threadIdx.x;
    int g = blockIdx.y;
    if (m >= M) return;
    float zr[CC];
    float z2 = 0.f;
    if (DIRECT) {
        int b = m >> 8, hw = m & 255;
        const float* src = zin + (size_t)b * (CC * 256) + hw;
        #pragma unroll
        for (int c = 0; c < CC; ++c) { zr[c] = src[c * 256]; z2 += zr[c] * zr[c]; }
    } else {
        #pragma unroll
        for (int c = 0; c < CC; ++c) { zr[c] = zin[(size_t)m * CC + c]; z2 += zr[c] * zr[c]; }
    }
    int v0 = g * gsz;
    const float* e = E + (size_t)v0 * CC;
    float best = 3.4e38f; int bv = v0;
    for (int v = v0; v < v0 + gsz; ++v, e += CC) {
        float d0 = 0.f, d1 = 0.f;   // two chains: break FMA latency serialization
        #pragma unroll
        for (int c = 0; c < CC; c += 2) {
            d0 = fmaf(zr[c],     e[c],     d0);
            d1 = fmaf(zr[c + 1], e[c + 1], d1);
        }
        float d = fmaf(-2.f, d0 + d1, z2 + e2[v]);
        if (d < best) { best = d; bv = v; }   // strict < == numpy first-min
    }
    bestd[(size_t)g * M + m] = best;
    bestv[(size_t)g * M + m] = bv;
}

// Fused: group-reduce -> gather+bicubic (v then h pass, LDS union) -> conv3x3 Phi
// -> f_hat += hf, f_rest -= hf.  grid = (4 co-groups, 64 batch), 256 threads.
__global__ __launch_bounds__(256) void fuse_k(const float* __restrict__ bestd,
                      const int* __restrict__ bestv, const float* __restrict__ E,
                      const float* __restrict__ pw, const float* __restrict__ pb,
                      float* __restrict__ f_hat, float* __restrict__ f_rest,
                      int pn, int grp, int kphi) {
    __shared__ float s_buf[CC * HH * 20];   // phase A: tmp[c][16][pn]; phase B+: hup[c][16][20]
    __shared__ float s_pw[8 * CC * 9];      // Phi weights for this co-group
    __shared__ int   s_idx[256];
    __shared__ float s_w[HH][4];
    __shared__ int   s_j[HH][4];
    const int t   = threadIdx.x;
    const int cog = blockIdx.x;   // 0..3 (8 output channels each)
    const int b   = blockIdx.y;   // 0..63
    const int M   = BB * pn * pn;

    // ---- phase 0: group-reduce argmin, bicubic weights, stage Phi weights ----
    if (t < pn * pn) {
        int m = b * pn * pn + t;
        float best = bestd[m]; int bv = bestv[m];
        for (int g = 1; g < grp; ++g) {
            float d = bestd[(size_t)g * M + m];
            if (d < best) { best = d; bv = bestv[(size_t)g * M + m]; }
        }
        s_idx[t] = bv;
    }
    if (t < HH) {
        double src = (t + 0.5) * (double)pn / 16.0 - 0.5;
        double fi = floor(src); int i0 = (int)fi; double tt = src - fi;
        #pragma unroll
        for (int k = 0; k < 4; ++k) {
            int j = i0 - 1 + k; j = j < 0 ? 0 : (j > pn - 1 ? pn - 1 : j);
            s_j[t][k] = j;
            s_w[t][k] = (float)cubicw((double)(k - 1) - tt);
        }
    }
    {
        const float* src = pw + ((size_t)(kphi * CC + cog * 8)) * CC * 9;
        for (int i = t; i < 8 * CC * 9; i += 256) s_pw[i] = src[i];
    }
    __syncthreads();

    // ---- phase A: vertical bicubic + gather: tmp[c][h][q] ----
    if (t < HH * pn) {
        int h = t / pn, q = t % pn;
        float acc[CC];
        #pragma unroll
        for (int c = 0; c < CC; ++c) acc[c] = 0.f;
        #pragma unroll
        for (int k = 0; k < 4; ++k) {
            float wv = s_w[h][k];
            int row = s_idx[s_j[h][k] * pn + q];
            const float4* er = (const float4*)(E + (size_t)row * CC);
            #pragma unroll
            for (int c4 = 0; c4 < CC / 4; ++c4) {
                float4 e4 = er[c4];
                acc[c4 * 4 + 0] = fmaf(wv, e4.x, acc[c4 * 4 + 0]);
                acc[c4 * 4 + 1] = fmaf(wv, e4.y, acc[c4 * 4 + 1]);
                acc[c4 * 4 + 2] = fmaf(wv, e4.z, acc[c4 * 4 + 2]);
                acc[c4 * 4 + 3] = fmaf(wv, e4.w, acc[c4 * 4 + 3]);
            }
        }
        #pragma unroll
        for (int c = 0; c < CC; ++c) s_buf[(c * HH + h) * pn + q] = acc[c];
    }
    __syncthreads();

    // ---- phase B: horizontal bicubic into registers, then rewrite as hup[c][16][20] ----
    {
        int h = t >> 4, w = t & 15;
        float acc[CC];
        #pragma unroll
        for (int c = 0; c < CC; ++c) acc[c] = 0.f;
        #pragma unroll
        for (int k = 0; k < 4; ++k) {
            float wh = s_w[w][k];
            int j = s_j[w][k];
            #pragma unroll
            for (int c = 0; c < CC; ++c)
                acc[c] = fmaf(wh, s_buf[(c * HH + h) * pn + j], acc[c]);
        }
        __syncthreads();   // all tmp reads complete before aliased writes
        #pragma unroll
        for (int c = 0; c < CC; ++c) s_buf[(c * HH + h) * 20 + 1 + w] = acc[c];
        if (w == 0) {
            #pragma unroll
            for (int c = 0; c < CC; ++c) s_buf[(c * HH + h) * 20] = 0.f;
        }
        if (w == 15) {
            #pragma unroll
            for (int c = 0; c < CC; ++c) {
                float* rr = &s_buf[(c * HH + h) * 20];
                rr[17] = 0.f; rr[18] = 0.f; rr[19] = 0.f;
            }
        }
    }
    __syncthreads();

    // ---- conv 3x3 Phi: thread -> (co, h, w0..w0+7) ----
    int col = t >> 5;                 // 0..7
    int co  = cog * 8 + col;
    int s   = t & 31;
    int h   = s >> 1;
    int w0  = (s & 1) * 8;
    float acc[8];
    float bias = pb[kphi * CC + co];
    #pragma unroll
    for (int o = 0; o < 8; ++o) acc[o] = bias;
    for (int ci = 0; ci < CC; ++ci) {
        const float* wrow = &s_pw[(col * CC + ci) * 9];
        #pragma unroll
        for (int kh = 0; kh < 3; ++kh) {
            int hh = h + kh - 1;
            if (hh < 0 || hh >= HH) continue;
            const float4* xr = (const float4*)&s_buf[(ci * HH + hh) * 20 + w0];
            float4 a0 = xr[0], a1 = xr[1], a2 = xr[2];
            float xf[12] = {a0.x, a0.y, a0.z, a0.w, a1.x, a1.y, a1.z, a1.w,
                            a2.x, a2.y, a2.z, a2.w};
            float k0 = wrow[kh * 3 + 0], k1 = wrow[kh * 3 + 1], k2 = wrow[kh * 3 + 2];
            #pragma unroll
            for (int o = 0; o < 8; ++o)
                acc[o] += xf[o] * k0 + xf[o + 1] * k1 + xf[o + 2] * k2;
        }
    }
    // ---- epilogue: hf = 0.5*h + 0.5*(conv+b); f_hat += hf; f_rest -= hf ----
    size_t base = ((size_t)(b * CC + co) * HH + h) * HH + w0;
    float hf[8];
    #pragma unroll
    for (int o = 0; o < 8; ++o) {
        float hv = s_buf[(co * HH + h) * 20 + 1 + w0 + o];
        hf[o] = 0.5f * hv + 0.5f * acc[o];
    }
    float4* fh = (float4*)(f_hat + base);
    float4* fr = (float4*)(f_rest + base);
    float4 v0 = fh[0], v1 = fh[1];
    v0.x += hf[0]; v0.y += hf[1]; v0.z += hf[2]; v0.w += hf[3];
    v1.x += hf[4]; v1.y += hf[5]; v1.z += hf[6]; v1.w += hf[7];
    fh[0] = v0; fh[1] = v1;
    float4 r0 = fr[0], r1 = fr[1];
    r0.x -= hf[0]; r0.y -= hf[1]; r0.z -= hf[2]; r0.w -= hf[3];
    r1.x -= hf[4]; r1.y -= hf[5]; r1.z -= hf[6]; r1.w -= hf[7];
    fr[0] = r0; fr[1] = r1;
}

extern "C" void kernel_launch(void* const* d_in, const int* in_sizes, int n_in,
                              void* d_out, int out_size, void* d_ws, size_t ws_size,
                              hipStream_t stream) {
    const float* f  = (const float*)d_in[0];
    const float* E  = (const float*)d_in[1];
    const float* pw = (const float*)d_in[2];
    const float* pb = (const float*)d_in[3];
    float* out = (float*)d_out;

    float* wsf    = (float*)d_ws;
    float* f_rest = wsf;
    float* z      = wsf + (size_t)NTOT;
    float* e2     = wsf + (size_t)2 * NTOT;
    float* bestd  = e2 + VV;
    int*   bestv  = (int*)(bestd + 262144);

    // numpy _phi_select, bit-exact in IEEE double (ties at si=2,7)
    int phik[10];
    {
        double start = 1.0 / 3.0 / 4.0;
        double stop  = 1.0 - 1.0 / 3.0 / 4.0;
        double step  = (stop - start) / 3.0;
        double ticks[4];
        for (int i = 0; i < 4; ++i) ticks[i] = (double)i * step + start;
        ticks[3] = stop;
        for (int si = 0; si < 10; ++si) {
            double s = (double)si / 9.0;
            int bk = 0; double bd = fabs(ticks[0] - s);
            for (int tq = 1; tq < 4; ++tq) {
                double d2 = fabs(ticks[tq] - s);
                if (d2 < bd) { bd = d2; bk = tq; }
            }
            phik[si] = bk;
        }
    }

    static const int pns[10] = {1, 2, 3, 4, 5, 6, 8, 10, 13, 16};
    static const int grps[10] = {64, 64, 64, 64, 64, 64, 32, 32, 16, 8};

    init_k<<<(NTOT + 255) / 256, 256, 0, stream>>>(f, E, f_rest, out, e2);

    for (int si = 0; si < 10; ++si) {
        int pn = pns[si];
        int M = BB * pn * pn;
        int grp = grps[si];
        int gsz = VV / grp;
        dim3 ag((M + 255) / 256, grp);
        if (si != 9) {
            int n1 = M * CC;
            down_k<<<(n1 + 255) / 256, 256, 0, stream>>>(f_rest, z, pn);
            argmin_k<0><<<ag, 256, 0, stream>>>(z, E, e2, bestd, bestv, M, gsz);
        } else {
            argmin_k<1><<<ag, 256, 0, stream>>>(f_rest, E, e2, bestd, bestv, M, gsz);
        }
        fuse_k<<<dim3(4, BB), 256, 0, stream>>>(bestd, bestv, E, pw, pb,
                                                out, f_rest, pn, grp, phik[si]);
    }
}